// Round 12
// baseline (165.293 us; speedup 1.0000x reference)
//
#include <hip/hip_runtime.h>

#define NHALF 4096
#define NROWS 8192
#define D 512
#define BM 128
#define BK 64
#define NB (NROWS / BM)            // 64
#define NTRI (NB * (NB + 1) / 2)   // 2080
#define TPB 4                      // tri-tiles per block
#define NBLK (NTRI / TPB)          // 520 = 8 * 65
#define CONV_BLOCKS 128
#define LOG2E 1.4426950408889634

typedef __bf16 bf16x8 __attribute__((ext_vector_type(8)));
typedef float  f32x4  __attribute__((ext_vector_type(4)));

__device__ __forceinline__ const float* row_ptr(const float* __restrict__ src,
                                                const float* __restrict__ tgt, int r) {
    return (r < NHALF) ? (src + (size_t)r * D) : (tgt + (size_t)(r - NHALF) * D);
}

// --- Pass A: fused convert fp32->bf16 + rowsq + colsum + sumsq + (last block) bandwidth ---
__global__ __launch_bounds__(256)
void conv_stats(const float* __restrict__ src, const float* __restrict__ tgt,
                __bf16* __restrict__ tot, float* __restrict__ sq,
                float* __restrict__ colsum, double* __restrict__ sumsq,
                unsigned* __restrict__ ticket, float* __restrict__ c2p_out) {
    __shared__ float cs_lds[4][512];
    __shared__ float wssq[4];
    __shared__ int lastFlag;
    __shared__ double red[256];
    int t = threadIdx.x, l = t & 63, w = t >> 6;
    int rbase = blockIdx.x * 64 + w * 16;

    float cs[8] = {0.f, 0.f, 0.f, 0.f, 0.f, 0.f, 0.f, 0.f};
    float ssq = 0.f;

    for (int rr = 0; rr < 16; ++rr) {
        int r = rbase + rr;
        const float* p = row_ptr(src, tgt, r) + l * 8;
        float4 v0 = *(const float4*)p;
        float4 v1 = *(const float4*)(p + 4);
        bf16x8 o;
        o[0] = (__bf16)v0.x; o[1] = (__bf16)v0.y; o[2] = (__bf16)v0.z; o[3] = (__bf16)v0.w;
        o[4] = (__bf16)v1.x; o[5] = (__bf16)v1.y; o[6] = (__bf16)v1.z; o[7] = (__bf16)v1.w;
        *(bf16x8*)&tot[(size_t)r * D + l * 8] = o;
        float s8 = v0.x*v0.x + v0.y*v0.y + v0.z*v0.z + v0.w*v0.w
                 + v1.x*v1.x + v1.y*v1.y + v1.z*v1.z + v1.w*v1.w;
        ssq += s8;
        cs[0] += v0.x; cs[1] += v0.y; cs[2] += v0.z; cs[3] += v0.w;
        cs[4] += v1.x; cs[5] += v1.y; cs[6] += v1.z; cs[7] += v1.w;
        float rsum = s8;
        for (int off = 32; off > 0; off >>= 1) rsum += __shfl_down(rsum, off);
        if (l == 0) sq[r] = rsum;
    }
#pragma unroll
    for (int j = 0; j < 8; ++j) cs_lds[w][l * 8 + j] = cs[j];
    for (int off = 32; off > 0; off >>= 1) ssq += __shfl_down(ssq, off);
    if (l == 0) wssq[w] = ssq;
    __syncthreads();
    int c0 = t * 2;
    float a = cs_lds[0][c0] + cs_lds[1][c0] + cs_lds[2][c0] + cs_lds[3][c0];
    float b = cs_lds[0][c0+1] + cs_lds[1][c0+1] + cs_lds[2][c0+1] + cs_lds[3][c0+1];
    atomicAdd(&colsum[c0], a);
    atomicAdd(&colsum[c0 + 1], b);
    if (t == 0) atomicAdd(sumsq, (double)(wssq[0] + wssq[1] + wssq[2] + wssq[3]));
    __syncthreads();

    if (t == 0) {
        __threadfence();
        unsigned old = atomicAdd(ticket, 1u);
        lastFlag = (old == CONV_BLOCKS - 1) ? 1 : 0;
    }
    __syncthreads();
    if (lastFlag) {
        float ca = atomicAdd(&colsum[t], 0.f);
        float cb = atomicAdd(&colsum[t + 256], 0.f);
        red[t] = (double)ca * ca + (double)cb * cb;
        __syncthreads();
        for (int s = 128; s > 0; s >>= 1) {
            if (t < s) red[t] += red[t + s];
            __syncthreads();
        }
        if (t == 0) {
            double ssqd = atomicAdd(sumsq, 0.0);
            double m = (double)NROWS;
            double sumL2 = 2.0 * m * ssqd - 2.0 * red[0];
            double bw = sumL2 / (m * m - m) / 4.0;
            c2p_out[0] = (float)(LOG2E / (16.0 * bw));
        }
    }
}

// --- Pass B: persistent 4-tile blocks; R5 core + rolling dbuf across tiles ---
__global__ __launch_bounds__(256, 2)
void mmd_main(const __bf16* __restrict__ tot, const float* __restrict__ sq,
              const float* __restrict__ c2p_p, double* __restrict__ S,
              unsigned* __restrict__ ticket, float* __restrict__ out) {
    int b = blockIdx.x;
    int nb = (b & 7) * (NBLK / 8) + (b >> 3);   // XCD-chunked (520 = 8*65, bijective)
    int ti0 = nb * TPB;

    // decode first tile, then sequential increments
    int bi = 0;
    while ((bi + 1) * NB - (bi + 1) * bi / 2 <= ti0) ++bi;
    int bj = bi + (ti0 - (bi * NB - bi * (bi - 1) / 2));

    int tbi[TPB], tbj[TPB];
    float tcoef[TPB];
#pragma unroll
    for (int tp = 0; tp < TPB; ++tp) {
        tbi[tp] = bi; tbj[tp] = bj;
        tcoef[tp] = ((bi == bj) ? 1.f : 2.f) * (((bi < 32) == (bj < 32)) ? 1.f : -1.f);
        ++bj; if (bj == NB) { ++bi; bj = bi; }
    }
    const __bf16* abp[TPB];
    const __bf16* bbp[TPB];
#pragma unroll
    for (int tp = 0; tp < TPB; ++tp) {
        abp[tp] = tot + (size_t)(tbi[tp] * BM) * D;
        bbp[tp] = tot + (size_t)(tbj[tp] * BM) * D;
    }

    // planar dbuf LDS: [sel][plane 0..7][row 0..127][8 bf16]
    __shared__ __align__(16) __bf16 As[2][8][BM][8];   // 32 KB
    __shared__ __align__(16) __bf16 Bs[2][8][BM][8];   // 32 KB

    int t = threadIdx.x, l = t & 63, w = t >> 6;
    int wr = w >> 1, wc = w & 1;       // 2x2 wave grid, 64x64 out each
    int r0 = l & 15, kg = l >> 4;

    auto stage = [&](int sel, const __bf16* ab, const __bf16* bb, int kt) {
#pragma unroll
        for (int i = 0; i < 4; ++i) {
            int g = i * 256 + t;            // 0..1023 = plane*128 + row
            int plane = g >> 7, row = g & 127;
            __builtin_amdgcn_global_load_lds(
                (const __attribute__((address_space(1))) void*)(ab + (size_t)row * D + kt * BK + plane * 8),
                (__attribute__((address_space(3))) void*)(&As[sel][0][0][0] + g * 8),
                16, 0, 0);
            __builtin_amdgcn_global_load_lds(
                (const __attribute__((address_space(1))) void*)(bb + (size_t)row * D + kt * BK + plane * 8),
                (__attribute__((address_space(3))) void*)(&Bs[sel][0][0][0] + g * 8),
                16, 0, 0);
        }
    };

    float c2p = c2p_p[0];
    float tc2 = c2p + c2p;

    f32x4 acc[4][4];
#pragma unroll
    for (int i = 0; i < 4; ++i)
#pragma unroll
        for (int j = 0; j < 4; ++j)
            acc[i][j] = (f32x4){0.f, 0.f, 0.f, 0.f};

    double wacc = 0.0;
    float ci[16], cj4[4];

    // Prologue: stage composite steps 0 and 1 (both tile 0); wait only step 0.
    stage(0, abp[0], bbp[0], 0);
    stage(1, abp[0], bbp[0], 1);
    asm volatile("s_waitcnt vmcnt(4)" ::: "memory");
    __builtin_amdgcn_s_barrier();

#pragma unroll
    for (int tp = 0; tp < TPB; ++tp) {
#pragma unroll
        for (int kt = 0; kt < 8; ++kt) {
            const int s = tp * 8 + kt;
            const int cur = s & 1;

            if (kt == 0) {   // prefetch this tile's sq-derived constants (pure overlap)
                int ib = tbi[tp] * BM + wr * 64 + (l >> 4) * 4;
                int jb = tbj[tp] * BM + wc * 64 + r0;
#pragma unroll
                for (int fi = 0; fi < 4; ++fi)
#pragma unroll
                    for (int j = 0; j < 4; ++j)
                        ci[fi * 4 + j] = c2p * sq[ib + fi * 16 + j];
#pragma unroll
                for (int fj = 0; fj < 4; ++fj) cj4[fj] = c2p * sq[jb + fj * 16];
            }

            __builtin_amdgcn_s_setprio(1);
#pragma unroll
            for (int ks = 0; ks < 2; ++ks) {
                bf16x8 af[4], bfr[4];
#pragma unroll
                for (int fi = 0; fi < 4; ++fi)
                    af[fi] = *(const bf16x8*)&As[cur][ks * 4 + kg][wr * 64 + fi * 16 + r0][0];
#pragma unroll
                for (int fj = 0; fj < 4; ++fj)
                    bfr[fj] = *(const bf16x8*)&Bs[cur][ks * 4 + kg][wc * 64 + fj * 16 + r0][0];
#pragma unroll
                for (int fi = 0; fi < 4; ++fi)
#pragma unroll
                    for (int fj = 0; fj < 4; ++fj)
                        acc[fi][fj] = __builtin_amdgcn_mfma_f32_16x16x32_bf16(af[fi], bfr[fj], acc[fi][fj], 0, 0, 0);
            }
            __builtin_amdgcn_s_setprio(0);
            asm volatile("" ::: "memory");      // keep ds_reads above BAR1
            __builtin_amdgcn_s_barrier();       // BAR1: all waves done reading buf[cur]

            if (s + 2 < TPB * 8) {              // stage composite step s+2 into just-read buffer
                const int s2 = s + 2;
                stage(cur, abp[s2 >> 3], bbp[s2 >> 3], s2 & 7);
            }

            if (kt == 7) {                      // epilogue for tile tp (overlaps in-flight stages)
                float local = 0.f;
#pragma unroll
                for (int fi = 0; fi < 4; ++fi) {
#pragma unroll
                    for (int fj = 0; fj < 4; ++fj) {
#pragma unroll
                        for (int j = 0; j < 4; ++j) {
                            float arg = fmaf(acc[fi][fj][j], tc2, -(ci[fi * 4 + j] + cj4[fj]));
                            float u = exp2f(arg);          // e^{-L2/16bw}
                            float ks2 = u;
                            u *= u; ks2 += u;              // /8bw
                            u *= u; ks2 += u;              // /4bw
                            u *= u; ks2 += u;              // /2bw
                            u *= u; ks2 += u;              // /bw
                            local += ks2;
                        }
                    }
                }
                for (int off = 32; off > 0; off >>= 1) local += __shfl_down(local, off);
                wacc += (double)(tcoef[tp] * local);       // lane0's value is the wave sum
#pragma unroll
                for (int i = 0; i < 4; ++i)
#pragma unroll
                    for (int j = 0; j < 4; ++j)
                        acc[i][j] = (f32x4){0.f, 0.f, 0.f, 0.f};
            }

            if (s < TPB * 8 - 2) {
                asm volatile("s_waitcnt vmcnt(4)" ::: "memory");   // step s+1 landed; s+2 in flight
            } else if (s == TPB * 8 - 2) {
                asm volatile("s_waitcnt vmcnt(0)" ::: "memory");   // drain last tile's loads
            }
            __builtin_amdgcn_s_barrier();       // BAR2: next buffer ready for all waves
        }
    }

    if (l == 0) atomicAdd(S, wacc);
    __syncthreads();
    if (t == 0) {
        __threadfence();
        unsigned old = atomicAdd(ticket, 1u);
        if (old == NBLK - 1) {
            double Sv = atomicAdd(S, 0.0);
            out[0] = (float)(Sv / ((double)NHALF * (double)NHALF));
        }
    }
}

extern "C" void kernel_launch(void* const* d_in, const int* in_sizes, int n_in,
                              void* d_out, int out_size, void* d_ws, size_t ws_size,
                              hipStream_t stream) {
    const float* src = (const float*)d_in[0];
    const float* tgt = (const float*)d_in[1];
    float* out = (float*)d_out;
    char* ws = (char*)d_ws;

    __bf16*   tot     = (__bf16*)ws;                       // 8 MB
    float*    sq      = (float*)(ws + 8388608);            // 32768 B
    float*    colsum  = (float*)(ws + 8388608 + 32768);    // 2048 B
    double*   sumsq   = (double*)(ws + 8388608 + 34816);   // 8 B
    double*   S       = (double*)(ws + 8388608 + 34824);   // 8 B
    unsigned* ticket1 = (unsigned*)(ws + 8388608 + 34832); // 4 B
    unsigned* ticket2 = (unsigned*)(ws + 8388608 + 34836); // 4 B
    float*    c2p     = (float*)(ws + 8388608 + 34840);    // 4 B

    hipMemsetAsync(ws + 8388608 + 32768, 0, 2072, stream);

    conv_stats<<<CONV_BLOCKS, 256, 0, stream>>>(src, tgt, tot, sq, colsum, sumsq, ticket1, c2p);
    mmd_main<<<NBLK, 256, 0, stream>>>(tot, sq, c2p, S, ticket2, out);
}